// Round 2
// baseline (755.798 us; speedup 1.0000x reference)
//
#include <hip/hip_runtime.h>
#include <hip/hip_bf16.h>

typedef unsigned short u16;

#define Bn 4
#define Nn 32768
#define Kn 128
#define Cn 256
#define Mn 1024
#define Hn 8
#define Dn 32
#define NCH 64   // n-chunks for to_basis1 (chunk = 512 rows)
#define MCH 16   // m-chunks for to_basis2 (chunk = 64 rows)

__device__ __forceinline__ float bf2f(u16 u) { return __uint_as_float(((unsigned)u) << 16); }
__device__ __forceinline__ u16 f2bf(float f) {
    union { __hip_bfloat16 h; u16 u; } cv;
    cv.h = __float2bfloat16(f);
    return cv.u;
}

// Typed-load helpers: T = u16 (bf16 storage) or float (fp32 storage)
template<typename T> struct LD;
template<> struct LD<u16> {
    static __device__ __forceinline__ float s(const u16* p) { return bf2f(*p); }
    static __device__ __forceinline__ void v4(const u16* p, float* o) {
        ushort4 u = *(const ushort4*)p;
        o[0] = bf2f(u.x); o[1] = bf2f(u.y); o[2] = bf2f(u.z); o[3] = bf2f(u.w);
    }
    static __device__ __forceinline__ void v8(const u16* p, float* o) {
        union { uint4 v; u16 h[8]; } u; u.v = *(const uint4*)p;
#pragma unroll
        for (int i = 0; i < 8; i++) o[i] = bf2f(u.h[i]);
    }
};
template<> struct LD<float> {
    static __device__ __forceinline__ float s(const float* p) { return *p; }
    static __device__ __forceinline__ void v4(const float* p, float* o) {
        float4 a = *(const float4*)p; o[0] = a.x; o[1] = a.y; o[2] = a.z; o[3] = a.w;
    }
    static __device__ __forceinline__ void v8(const float* p, float* o) { v4(p, o); v4(p + 4, o + 4); }
};
template<typename T> __device__ __forceinline__ int fmode() { return sizeof(T) == 4 ? 1 : 0; }

__device__ __forceinline__ void st4(u16* p, float a, float b, float c, float d) {
    ushort4 w; w.x = f2bf(a); w.y = f2bf(b); w.z = f2bf(c); w.w = f2bf(d);
    *(ushort4*)p = w;
}
__device__ __forceinline__ void st4(float* p, float a, float b, float c, float d) {
    *(float4*)p = make_float4(a, b, c, d);
}

// ---------------------------------------------------------------------------
// Probe: decide whether raw inputs are bf16 (flag=0) or fp32 (flag=1).
// Reads first 64K u16 of x as bf16. True bf16 N(0,1): no |v|>1e4, no NaN.
// fp32-reinterpreted: ~45% of even halves are garbage with huge/NaN decode.
// ---------------------------------------------------------------------------
__global__ __launch_bounds__(256) void k_probe(const u16* __restrict__ x, int* __restrict__ flag)
{
    const int t = threadIdx.x;
    int cnt = 0;
    for (int i = t; i < 65536; i += 256) {
        const float v = bf2f(x[i]);
        if (!(fabsf(v) <= 1e4f)) cnt++;   // catches huge and NaN
    }
    __shared__ int sb[256];
    sb[t] = cnt; __syncthreads();
    for (int o = 128; o > 0; o >>= 1) {
        if (t < o) sb[t] += sb[t + o];
        __syncthreads();
    }
    if (t == 0) *flag = (sb[0] > 64) ? 1 : 0;
}

// ---------------------------------------------------------------------------
// K1: to_basis #1.  part[b][nch][k][c] = sum_{n in chunk} evecs[b,n,k] * x[b,n,c]*mass[b,n]
// ---------------------------------------------------------------------------
template<typename T>
__global__ __launch_bounds__(256) void k_tobasis1(
    const T* __restrict__ x, const T* __restrict__ mass,
    const T* __restrict__ evecs, float* __restrict__ part, const int* __restrict__ flag)
{
    if (*flag != fmode<T>()) return;
    const int nch = blockIdx.x, ct = blockIdx.y, b = blockIdx.z;
    const int n0 = nch * (Nn / NCH);
    const int c0 = ct * 128;
    __shared__ float ev[32][128];
    __shared__ float xm[32][128];
    const int t = threadIdx.x, tx = t & 15, ty = t >> 4;
    float acc[8][8];
#pragma unroll
    for (int i = 0; i < 8; i++)
#pragma unroll
        for (int j = 0; j < 8; j++) acc[i][j] = 0.f;

    const int lr = t >> 3;        // 0..31
    const int lc = (t & 7) * 16;  // 0..112
    for (int s = 0; s < Nn / NCH; s += 32) {
        const size_t nrow = (size_t)b * Nn + n0 + s + lr;
        {
            float eb[16], xb[16];
            LD<T>::v8(evecs + nrow * Kn + lc, eb);
            LD<T>::v8(evecs + nrow * Kn + lc + 8, eb + 8);
            const float mv = LD<T>::s(mass + nrow);
            LD<T>::v8(x + nrow * Cn + c0 + lc, xb);
            LD<T>::v8(x + nrow * Cn + c0 + lc + 8, xb + 8);
#pragma unroll
            for (int i = 0; i < 16; i++) { ev[lr][lc + i] = eb[i]; xm[lr][lc + i] = xb[i] * mv; }
        }
        __syncthreads();
#pragma unroll 4
        for (int nn = 0; nn < 32; nn++) {
            float4 e0 = *(const float4*)&ev[nn][ty * 4];
            float4 e1 = *(const float4*)&ev[nn][64 + ty * 4];
            float4 x0 = *(const float4*)&xm[nn][tx * 4];
            float4 x1 = *(const float4*)&xm[nn][64 + tx * 4];
            float ee[8] = {e0.x, e0.y, e0.z, e0.w, e1.x, e1.y, e1.z, e1.w};
            float xx[8] = {x0.x, x0.y, x0.z, x0.w, x1.x, x1.y, x1.z, x1.w};
#pragma unroll
            for (int i = 0; i < 8; i++)
#pragma unroll
                for (int j = 0; j < 8; j++) acc[i][j] += ee[i] * xx[j];
        }
        __syncthreads();
    }
    float* dst = part + ((size_t)b * NCH + nch) * (Kn * Cn);
#pragma unroll
    for (int i = 0; i < 8; i++) {
        const int k = (i < 4) ? (ty * 4 + i) : (64 + ty * 4 + i - 4);
        *(float4*)(dst + (size_t)k * Cn + c0 + tx * 4) =
            make_float4(acc[i][0], acc[i][1], acc[i][2], acc[i][3]);
        *(float4*)(dst + (size_t)k * Cn + c0 + 64 + tx * 4) =
            make_float4(acc[i][4], acc[i][5], acc[i][6], acc[i][7]);
    }
}

// ---------------------------------------------------------------------------
// Reduce chunk partials and apply heat coefficient exp(-eval * t_c)
// ---------------------------------------------------------------------------
template<typename T>
__global__ __launch_bounds__(256) void k_reduce(
    const float* __restrict__ part, int nchunks,
    const T* __restrict__ evals, const T* __restrict__ tvec,
    float* __restrict__ spec, const int* __restrict__ flag)
{
    if (*flag != fmode<T>()) return;
    const int b = blockIdx.x >> 7, k = blockIdx.x & 127, c = threadIdx.x;
    float ssum = 0.f;
    const float* p = part + ((size_t)b * nchunks * Kn + k) * Cn + c;
    for (int j = 0; j < nchunks; j++) ssum += p[(size_t)j * Kn * Cn];
    const float lam = LD<T>::s(evals + b * Kn + k);
    const float tt = fmaxf(LD<T>::s(tvec + c), 1e-8f);
    spec[((size_t)b * Kn + k) * Cn + c] = ssum * __expf(-lam * tt);
}

// ---------------------------------------------------------------------------
// Gather evecs & mass at far indices (fp32 scratch copies)
// ---------------------------------------------------------------------------
template<typename T>
__global__ __launch_bounds__(128) void k_gather(
    const T* __restrict__ evecs, const T* __restrict__ mass,
    const int* __restrict__ far, float* __restrict__ evf, float* __restrict__ massf,
    const int* __restrict__ flag)
{
    if (*flag != fmode<T>()) return;
    const int row = blockIdx.x;  // b*M + m
    const int b = row >> 10;
    const int idx = far[row];
    const int t = threadIdx.x;
    evf[(size_t)row * Kn + t] = LD<T>::s(evecs + ((size_t)b * Nn + idx) * Kn + t);
    if (t == 0) massf[row] = LD<T>::s(mass + (size_t)b * Nn + idx);
}

// ---------------------------------------------------------------------------
// Generic 64x64-tile GEMM: out[row][c'] = X[row][0:KD] @ W[KD][256] (+bias)(*mass)
// ---------------------------------------------------------------------------
struct G3 {
    const void* W[3];
    const void* bias[3];
    float* out[3];
};

template<typename T, int KD, bool PERB, bool MMASS, bool CHECK>
__global__ __launch_bounds__(256) void k_gemm64(
    const float* __restrict__ X, G3 g, const float* __restrict__ massf,
    const int* __restrict__ flag)
{
    if (CHECK && *flag != fmode<T>()) return;
    const int mt = blockIdx.x, ct = blockIdx.y, z = blockIdx.z;
    const int row0 = mt * 64, c0 = ct * 64;
    const int b = row0 >> 10;
    const T* Wp = (const T*)g.W[z];
    const T* bias = (const T*)g.bias[z];
    float* out = g.out[z];
    const size_t woff = PERB ? (size_t)b * KD * 256 : 0;

    __shared__ float xT[32][68];   // 68*4 = 272 B rows (16B-aligned)
    __shared__ float wl[32][64];
    const int t = threadIdx.x, tx = t & 15, ty = t >> 4;
    float acc[4][4] = {};

    for (int k0 = 0; k0 < KD; k0 += 32) {
        {
            const int m = t >> 2, cc0 = (t & 3) * 8;
            const float* xs = X + (size_t)(row0 + m) * KD + k0 + cc0;
            float4 a0 = *(const float4*)xs, a1 = *(const float4*)(xs + 4);
            xT[cc0 + 0][m] = a0.x; xT[cc0 + 1][m] = a0.y; xT[cc0 + 2][m] = a0.z; xT[cc0 + 3][m] = a0.w;
            xT[cc0 + 4][m] = a1.x; xT[cc0 + 5][m] = a1.y; xT[cc0 + 6][m] = a1.z; xT[cc0 + 7][m] = a1.w;
        }
        {
            const int cc = t >> 3, col = (t & 7) * 8;
            float wb[8];
            LD<T>::v8(Wp + woff + (size_t)(k0 + cc) * 256 + c0 + col, wb);
#pragma unroll
            for (int i = 0; i < 8; i++) wl[cc][col + i] = wb[i];
        }
        __syncthreads();
#pragma unroll 8
        for (int cc = 0; cc < 32; cc++) {
            float4 xv = *(const float4*)&xT[cc][ty * 4];
            float4 wv = *(const float4*)&wl[cc][tx * 4];
            float xa[4] = {xv.x, xv.y, xv.z, xv.w};
            float wa[4] = {wv.x, wv.y, wv.z, wv.w};
#pragma unroll
            for (int i = 0; i < 4; i++)
#pragma unroll
                for (int j = 0; j < 4; j++) acc[i][j] += xa[i] * wa[j];
        }
        __syncthreads();
    }
    float bj[4] = {0.f, 0.f, 0.f, 0.f};
    if (bias) {
#pragma unroll
        for (int j = 0; j < 4; j++) bj[j] = LD<T>::s(bias + c0 + tx * 4 + j);
    }
#pragma unroll
    for (int i = 0; i < 4; i++) {
        const int row = row0 + ty * 4 + i;
        const float mm = MMASS ? massf[row] : 1.f;
        *(float4*)(out + (size_t)row * 256 + c0 + tx * 4) =
            make_float4((acc[i][0] + bj[0]) * mm, (acc[i][1] + bj[1]) * mm,
                        (acc[i][2] + bj[2]) * mm, (acc[i][3] + bj[3]) * mm);
    }
}

// ---------------------------------------------------------------------------
// GroupNorm stats: per (b, g) mean/invstd over M x 8 channels
// ---------------------------------------------------------------------------
__global__ __launch_bounds__(256) void k_gnstats(const float* __restrict__ xfar, float* __restrict__ gst)
{
    const int b = blockIdx.x >> 5, g = blockIdx.x & 31;
    const int t = threadIdx.x;
    float s = 0.f, s2 = 0.f;
#pragma unroll
    for (int i = 0; i < 4; i++) {
        const int m = t * 4 + i;
        const float* p = xfar + ((size_t)b * Mn + m) * Cn + g * 8;
        float4 a = *(const float4*)p;
        float4 c = *(const float4*)(p + 4);
        s += a.x + a.y + a.z + a.w + c.x + c.y + c.z + c.w;
        s2 += a.x * a.x + a.y * a.y + a.z * a.z + a.w * a.w +
              c.x * c.x + c.y * c.y + c.z * c.z + c.w * c.w;
    }
    __shared__ float sb[256], sb2[256];
    sb[t] = s; sb2[t] = s2;
    __syncthreads();
    for (int o = 128; o > 0; o >>= 1) {
        if (t < o) { sb[t] += sb[t + o]; sb2[t] += sb2[t + o]; }
        __syncthreads();
    }
    if (t == 0) {
        const float mean = sb[0] * (1.f / 8192.f);
        const float var = sb2[0] * (1.f / 8192.f) - mean * mean;
        gst[2 * blockIdx.x] = mean;
        gst[2 * blockIdx.x + 1] = rsqrtf(var + 1e-6f);
    }
}

template<typename T>
__global__ __launch_bounds__(256) void k_gnapply(
    const float* __restrict__ xfar, const float* __restrict__ gst,
    const T* __restrict__ gw, const T* __restrict__ gb, float* __restrict__ xn,
    const int* __restrict__ flag)
{
    if (*flag != fmode<T>()) return;
    const int idx = (blockIdx.x * 256 + threadIdx.x) * 4;
    const int c = idx & 255;
    const int row = idx >> 8;
    const int b = row >> 10;
    const int g = c >> 3;
    const float2 st = *(const float2*)&gst[2 * (b * 32 + g)];
    float4 vv = *(const float4*)&xfar[idx];
    float w4[4], b4[4];
    LD<T>::v4(gw + c, w4);
    LD<T>::v4(gb + c, b4);
    float4 o;
    o.x = (vv.x - st.x) * st.y * w4[0] + b4[0];
    o.y = (vv.y - st.x) * st.y * w4[1] + b4[1];
    o.z = (vv.z - st.x) * st.y * w4[2] + b4[2];
    o.w = (vv.w - st.x) * st.y * w4[3] + b4[3];
    *(float4*)&xn[idx] = o;
}

// ---------------------------------------------------------------------------
// Attention: K-split flash over fp32 ws buffers (dtype-agnostic)
// ---------------------------------------------------------------------------
__global__ __launch_bounds__(256) void k_attn(
    const float* __restrict__ q, const float* __restrict__ kbuf, const float* __restrict__ vbuf,
    float* __restrict__ pacc, float* __restrict__ pm, float* __restrict__ pl)
{
    const int qt = blockIdx.x, seg = blockIdx.y, bh = blockIdx.z;
    const int b = bh >> 3, h = bh & 7;
    const int t = threadIdx.x;
    const int m = qt * 256 + t;
    __shared__ float kl[32][40];
    __shared__ float vl[32][40];
    float qr[32];
    const float* qp = q + ((size_t)b * Mn + m) * Cn + h * Dn;
#pragma unroll
    for (int i = 0; i < 32; i += 4) {
        float4 a = *(const float4*)(qp + i);
        qr[i] = a.x; qr[i + 1] = a.y; qr[i + 2] = a.z; qr[i + 3] = a.w;
    }
    float mx = -1e30f, l = 0.f;
    float acc[32] = {};
    const float scale = 0.17677669529663687f;  // 1/sqrt(32)
    const int lr = t >> 3, lc = (t & 7) * 4;
    for (int k0 = seg * 256; k0 < seg * 256 + 256; k0 += 32) {
        {
            const size_t krow = ((size_t)b * Mn + k0 + lr) * Cn + h * Dn + lc;
            float4 a = *(const float4*)(kbuf + krow);
            kl[lr][lc] = a.x; kl[lr][lc + 1] = a.y; kl[lr][lc + 2] = a.z; kl[lr][lc + 3] = a.w;
            float4 bv4 = *(const float4*)(vbuf + krow);
            vl[lr][lc] = bv4.x; vl[lr][lc + 1] = bv4.y; vl[lr][lc + 2] = bv4.z; vl[lr][lc + 3] = bv4.w;
        }
        __syncthreads();
        float s[32];
#pragma unroll 4
        for (int j = 0; j < 32; j++) {
            float d = 0.f;
#pragma unroll
            for (int i = 0; i < 32; i += 4) {
                float4 a = *(const float4*)&kl[j][i];
                d += qr[i] * a.x + qr[i + 1] * a.y + qr[i + 2] * a.z + qr[i + 3] * a.w;
            }
            s[j] = d * scale;
        }
        float tm = mx;
#pragma unroll
        for (int j = 0; j < 32; j++) tm = fmaxf(tm, s[j]);
        const float r = __expf(mx - tm);
        l *= r;
#pragma unroll
        for (int i = 0; i < 32; i++) acc[i] *= r;
#pragma unroll 4
        for (int j = 0; j < 32; j++) {
            const float p = __expf(s[j] - tm);
            l += p;
#pragma unroll
            for (int i = 0; i < 32; i += 4) {
                float4 a = *(const float4*)&vl[j][i];
                acc[i] += p * a.x; acc[i + 1] += p * a.y; acc[i + 2] += p * a.z; acc[i + 3] += p * a.w;
            }
        }
        mx = tm;
        __syncthreads();
    }
    const size_t pr = (((size_t)seg * Bn + b) * Hn + h) * Mn + m;
    pm[pr] = mx; pl[pr] = l;
    float* pa = pacc + pr * 32;
#pragma unroll
    for (int i = 0; i < 32; i += 4)
        *(float4*)(pa + i) = make_float4(acc[i], acc[i + 1], acc[i + 2], acc[i + 3]);
}

__global__ __launch_bounds__(256) void k_comb(
    const float* __restrict__ pacc, const float* __restrict__ pm, const float* __restrict__ pl,
    float* __restrict__ att)
{
    const int t = threadIdx.x;
    const size_t row = (size_t)blockIdx.x * 8 + (t >> 5);  // (b*8+h)*1024 + m
    const int j = t & 31;
    float M = -1e30f;
#pragma unroll
    for (int s = 0; s < 4; s++) M = fmaxf(M, pm[(size_t)s * 32768 + row]);
    float L = 0.f, a = 0.f;
#pragma unroll
    for (int s = 0; s < 4; s++) {
        const float w = __expf(pm[(size_t)s * 32768 + row] - M);
        L += w * pl[(size_t)s * 32768 + row];
        a += w * pacc[((size_t)s * 32768 + row) * 32 + j];
    }
    const int bh = (int)(row >> 10);
    const int mrow = (int)(row & 1023);
    const int b = bh >> 3, h = bh & 7;
    att[((size_t)b * Mn + mrow) * Cn + h * 32 + j] = a / L;
}

// ---------------------------------------------------------------------------
// to_basis #2 over far rows only (fp32 inputs from ws; dtype-agnostic)
// ---------------------------------------------------------------------------
__global__ __launch_bounds__(256) void k_tobasis2(
    const float* __restrict__ evf, const float* __restrict__ xo, float* __restrict__ part)
{
    const int mch = blockIdx.x, ct = blockIdx.y, b = blockIdx.z;
    const int m0 = mch * (Mn / MCH);
    const int c0 = ct * 128;
    __shared__ float ev[32][128];
    __shared__ float xm[32][128];
    const int t = threadIdx.x, tx = t & 15, ty = t >> 4;
    float acc[8][8];
#pragma unroll
    for (int i = 0; i < 8; i++)
#pragma unroll
        for (int j = 0; j < 8; j++) acc[i][j] = 0.f;
    const int lr = t >> 3, lc = (t & 7) * 16;
    for (int s = 0; s < Mn / MCH; s += 32) {
        const size_t mrow = (size_t)b * Mn + m0 + s + lr;
        {
            const float* es = evf + mrow * Kn + lc;
            *(float4*)&ev[lr][lc] = *(const float4*)es;
            *(float4*)&ev[lr][lc + 4] = *(const float4*)(es + 4);
            *(float4*)&ev[lr][lc + 8] = *(const float4*)(es + 8);
            *(float4*)&ev[lr][lc + 12] = *(const float4*)(es + 12);
            const float* xs = xo + mrow * Cn + c0 + lc;
            *(float4*)&xm[lr][lc] = *(const float4*)xs;
            *(float4*)&xm[lr][lc + 4] = *(const float4*)(xs + 4);
            *(float4*)&xm[lr][lc + 8] = *(const float4*)(xs + 8);
            *(float4*)&xm[lr][lc + 12] = *(const float4*)(xs + 12);
        }
        __syncthreads();
#pragma unroll 4
        for (int nn = 0; nn < 32; nn++) {
            float4 e0 = *(const float4*)&ev[nn][ty * 4];
            float4 e1 = *(const float4*)&ev[nn][64 + ty * 4];
            float4 x0 = *(const float4*)&xm[nn][tx * 4];
            float4 x1 = *(const float4*)&xm[nn][64 + tx * 4];
            float ee[8] = {e0.x, e0.y, e0.z, e0.w, e1.x, e1.y, e1.z, e1.w};
            float xx[8] = {x0.x, x0.y, x0.z, x0.w, x1.x, x1.y, x1.z, x1.w};
#pragma unroll
            for (int i = 0; i < 8; i++)
#pragma unroll
                for (int j = 0; j < 8; j++) acc[i][j] += ee[i] * xx[j];
        }
        __syncthreads();
    }
    float* dst = part + ((size_t)b * MCH + mch) * (Kn * Cn);
#pragma unroll
    for (int i = 0; i < 8; i++) {
        const int k = (i < 4) ? (ty * 4 + i) : (64 + ty * 4 + i - 4);
        *(float4*)(dst + (size_t)k * Cn + c0 + tx * 4) =
            make_float4(acc[i][0], acc[i][1], acc[i][2], acc[i][3]);
        *(float4*)(dst + (size_t)k * Cn + c0 + 64 + tx * 4) =
            make_float4(acc[i][4], acc[i][5], acc[i][6], acc[i][7]);
    }
}

// ---------------------------------------------------------------------------
// from_basis #2: out[b,n,c] = out_w[c] * sum_k evecs[b,n,k]*spec2'[b,k,c]
// ---------------------------------------------------------------------------
template<typename T>
__global__ __launch_bounds__(256) void k_frombasis2(
    const T* __restrict__ evecs, const float* __restrict__ spec,
    const T* __restrict__ outw, T* __restrict__ out, const int* __restrict__ flag)
{
    if (*flag != fmode<T>()) return;
    const int nt = blockIdx.x, ct = blockIdx.y, b = blockIdx.z;
    const int n0 = nt * 128, c0 = ct * 128;
    __shared__ float evT[32][132];
    __shared__ float sp[32][128];
    const int t = threadIdx.x, tx = t & 15, ty = t >> 4;
    float acc[8][8];
#pragma unroll
    for (int i = 0; i < 8; i++)
#pragma unroll
        for (int j = 0; j < 8; j++) acc[i][j] = 0.f;
    const int en = t >> 1, ek0 = (t & 1) * 16;
    const int sr = t >> 3, sc = (t & 7) * 16;
    for (int k0 = 0; k0 < Kn; k0 += 32) {
        {
            float eb[16];
            const T* es = evecs + ((size_t)b * Nn + n0 + en) * Kn + k0 + ek0;
            LD<T>::v8(es, eb);
            LD<T>::v8(es + 8, eb + 8);
#pragma unroll
            for (int i = 0; i < 16; i++) evT[ek0 + i][en] = eb[i];
            const float* ss = spec + ((size_t)b * Kn + k0 + sr) * Cn + c0 + sc;
            *(float4*)&sp[sr][sc] = *(const float4*)ss;
            *(float4*)&sp[sr][sc + 4] = *(const float4*)(ss + 4);
            *(float4*)&sp[sr][sc + 8] = *(const float4*)(ss + 8);
            *(float4*)&sp[sr][sc + 12] = *(const float4*)(ss + 12);
        }
        __syncthreads();
#pragma unroll 4
        for (int kk2 = 0; kk2 < 32; kk2++) {
            float4 e0 = *(const float4*)&evT[kk2][ty * 4];
            float4 e1 = *(const float4*)&evT[kk2][64 + ty * 4];
            float4 s0 = *(const float4*)&sp[kk2][tx * 4];
            float4 s1 = *(const float4*)&sp[kk2][64 + tx * 4];
            float ee[8] = {e0.x, e0.y, e0.z, e0.w, e1.x, e1.y, e1.z, e1.w};
            float sv[8] = {s0.x, s0.y, s0.z, s0.w, s1.x, s1.y, s1.z, s1.w};
#pragma unroll
            for (int i = 0; i < 8; i++)
#pragma unroll
                for (int j = 0; j < 8; j++) acc[i][j] += ee[i] * sv[j];
        }
        __syncthreads();
    }
    float ow[8];
#pragma unroll
    for (int j = 0; j < 8; j++) {
        const int c = c0 + ((j < 4) ? (tx * 4 + j) : (64 + tx * 4 + j - 4));
        ow[j] = fmaxf(LD<T>::s(outw + c), 1e-8f);
    }
#pragma unroll
    for (int i = 0; i < 8; i++) {
        const int n = n0 + ((i < 4) ? (ty * 4 + i) : (64 + ty * 4 + i - 4));
        T* od = out + ((size_t)b * Nn + n) * Cn + c0;
        st4(od + tx * 4, acc[i][0] * ow[0], acc[i][1] * ow[1], acc[i][2] * ow[2], acc[i][3] * ow[3]);
        st4(od + 64 + tx * 4, acc[i][4] * ow[4], acc[i][5] * ow[5], acc[i][6] * ow[6], acc[i][7] * ow[7]);
    }
}

// ---------------------------------------------------------------------------
extern "C" void kernel_launch(void* const* d_in, const int* in_sizes, int n_in,
                              void* d_out, int out_size, void* d_ws, size_t ws_size,
                              hipStream_t stream)
{
    const void* x     = d_in[0];
    const void* mass  = d_in[1];
    const void* evals = d_in[2];
    const void* evecs = d_in[3];
    const int*  far   = (const int*)d_in[4];
    const void* t_in  = d_in[5];
    const void* t_out = d_in[6];
    const void* gn_w  = d_in[7];
    const void* gn_b  = d_in[8];
    const void* Wq    = d_in[9];
    const void* bq    = d_in[10];
    const void* Wk    = d_in[11];
    const void* bk    = d_in[12];
    const void* Wv    = d_in[13];
    const void* bv    = d_in[14];
    const void* Wo    = d_in[15];
    const void* bo    = d_in[16];
    const void* outw  = d_in[17];
    float* ws = (float*)d_ws;

    // workspace layout (floats); region A is reused: part1 -> pacc -> part2
    float* A     = ws;               // 8,388,608
    float* spec1 = ws + 8388608;     // 131,072
    float* evf   = spec1 + 131072;   // 524,288
    float* massf = evf + 524288;     // 4,096
    float* xfar  = massf + 4096;     // 1,048,576
    float* gst   = xfar + 1048576;   // 256
    float* xn    = gst + 256;        // 1,048,576
    float* q     = xn + 1048576;     // 1,048,576
    float* kk    = q + 1048576;      // 1,048,576
    float* v     = kk + 1048576;     // 1,048,576
    float* pm    = v + 1048576;      // 131,072
    float* pl    = pm + 131072;      // 131,072
    float* att   = pl + 131072;      // 1,048,576
    float* xo    = att + 1048576;    // 1,048,576
    float* spec2 = xo + 1048576;     // 131,072
    int*  flag   = (int*)(spec2 + 131072);
    float* pacc  = A;                // alias: part1 dead after k_reduce
    float* part2 = A;                // alias: pacc dead after k_comb

    k_probe<<<1, 256, 0, stream>>>((const u16*)x, flag);

    k_tobasis1<u16><<<dim3(NCH, 2, Bn), 256, 0, stream>>>((const u16*)x, (const u16*)mass, (const u16*)evecs, A, flag);
    k_tobasis1<float><<<dim3(NCH, 2, Bn), 256, 0, stream>>>((const float*)x, (const float*)mass, (const float*)evecs, A, flag);

    k_reduce<u16><<<Bn * Kn, Cn, 0, stream>>>(A, NCH, (const u16*)evals, (const u16*)t_in, spec1, flag);
    k_reduce<float><<<Bn * Kn, Cn, 0, stream>>>(A, NCH, (const float*)evals, (const float*)t_in, spec1, flag);

    k_gather<u16><<<Bn * Mn, Kn, 0, stream>>>((const u16*)evecs, (const u16*)mass, far, evf, massf, flag);
    k_gather<float><<<Bn * Mn, Kn, 0, stream>>>((const float*)evecs, (const float*)mass, far, evf, massf, flag);

    {   // from_basis1: W = spec1 (fp32 ws) — dtype-agnostic, run once
        G3 g{};
        g.W[0] = spec1; g.bias[0] = nullptr; g.out[0] = xfar;
        k_gemm64<float, 128, true, false, false><<<dim3(64, 4, 1), 256, 0, stream>>>(evf, g, nullptr, flag);
    }
    k_gnstats<<<Bn * 32, 256, 0, stream>>>(xfar, gst);
    k_gnapply<u16><<<1024, 256, 0, stream>>>(xfar, gst, (const u16*)gn_w, (const u16*)gn_b, xn, flag);
    k_gnapply<float><<<1024, 256, 0, stream>>>(xfar, gst, (const float*)gn_w, (const float*)gn_b, xn, flag);
    {
        G3 g{};
        g.W[0] = Wq; g.W[1] = Wk; g.W[2] = Wv;
        g.bias[0] = bq; g.bias[1] = bk; g.bias[2] = bv;
        g.out[0] = q; g.out[1] = kk; g.out[2] = v;
        k_gemm64<u16, 256, false, false, true><<<dim3(64, 4, 3), 256, 0, stream>>>(xn, g, nullptr, flag);
        k_gemm64<float, 256, false, false, true><<<dim3(64, 4, 3), 256, 0, stream>>>(xn, g, nullptr, flag);
    }
    k_attn<<<dim3(4, 4, 32), 256, 0, stream>>>(q, kk, v, pacc, pm, pl);
    k_comb<<<4096, 256, 0, stream>>>(pacc, pm, pl, att);
    {
        G3 g{};
        g.W[0] = Wo; g.bias[0] = bo; g.out[0] = xo;
        k_gemm64<u16, 256, false, true, true><<<dim3(64, 4, 1), 256, 0, stream>>>(att, g, massf, flag);
        k_gemm64<float, 256, false, true, true><<<dim3(64, 4, 1), 256, 0, stream>>>(att, g, massf, flag);
    }
    k_tobasis2<<<dim3(MCH, 2, Bn), 256, 0, stream>>>(evf, xo, part2);
    k_reduce<u16><<<Bn * Kn, Cn, 0, stream>>>(part2, MCH, (const u16*)evals, (const u16*)t_out, spec2, flag);
    k_reduce<float><<<Bn * Kn, Cn, 0, stream>>>(part2, MCH, (const float*)evals, (const float*)t_out, spec2, flag);

    k_frombasis2<u16><<<dim3(256, 2, Bn), 256, 0, stream>>>((const u16*)evecs, spec2, (const u16*)outw, (u16*)d_out, flag);
    k_frombasis2<float><<<dim3(256, 2, Bn), 256, 0, stream>>>((const float*)evecs, spec2, (const float*)outw, (float*)d_out, flag);
}

// Round 3
// 699.437 us; speedup vs baseline: 1.0806x; 1.0806x over previous
//
#include <hip/hip_runtime.h>
#include <hip/hip_bf16.h>

// All inputs and the output are fp32 (established empirically in rounds 1-2:
// bf16 interpretation NaN'd; fp32 probe branch passed with absmax 3e-05).

#define Bn 4
#define Nn 32768
#define Kn 128
#define Cn 256
#define Mn 1024
#define Hn 8
#define Dn 32
#define NCH 64   // n-chunks for to_basis1 (chunk = 512 rows)
#define MCH 16   // m-chunks for to_basis2 (chunk = 64 rows)

// ---------------------------------------------------------------------------
// K1: to_basis #1.  part[b][nch][k][c] = sum_{n in chunk} evecs[b,n,k] * x[b,n,c]*mass[b,n]
// ---------------------------------------------------------------------------
__global__ __launch_bounds__(256) void k_tobasis1(
    const float* __restrict__ x, const float* __restrict__ mass,
    const float* __restrict__ evecs, float* __restrict__ part)
{
    const int nch = blockIdx.x, ct = blockIdx.y, b = blockIdx.z;
    const int n0 = nch * (Nn / NCH);
    const int c0 = ct * 128;
    __shared__ float ev[32][128];
    __shared__ float xm[32][128];
    const int t = threadIdx.x, tx = t & 15, ty = t >> 4;
    float acc[8][8];
#pragma unroll
    for (int i = 0; i < 8; i++)
#pragma unroll
        for (int j = 0; j < 8; j++) acc[i][j] = 0.f;

    const int lr = t >> 3;        // 0..31
    const int lc = (t & 7) * 16;  // 0..112
    for (int s = 0; s < Nn / NCH; s += 32) {
        const size_t nrow = (size_t)b * Nn + n0 + s + lr;
        {
            const float* es = evecs + nrow * Kn + lc;
            *(float4*)&ev[lr][lc]      = *(const float4*)es;
            *(float4*)&ev[lr][lc + 4]  = *(const float4*)(es + 4);
            *(float4*)&ev[lr][lc + 8]  = *(const float4*)(es + 8);
            *(float4*)&ev[lr][lc + 12] = *(const float4*)(es + 12);
            const float mv = mass[nrow];
            const float* xs = x + nrow * Cn + c0 + lc;
            float4 a0 = *(const float4*)xs, a1 = *(const float4*)(xs + 4);
            float4 a2 = *(const float4*)(xs + 8), a3 = *(const float4*)(xs + 12);
            xm[lr][lc + 0] = a0.x * mv; xm[lr][lc + 1] = a0.y * mv; xm[lr][lc + 2] = a0.z * mv; xm[lr][lc + 3] = a0.w * mv;
            xm[lr][lc + 4] = a1.x * mv; xm[lr][lc + 5] = a1.y * mv; xm[lr][lc + 6] = a1.z * mv; xm[lr][lc + 7] = a1.w * mv;
            xm[lr][lc + 8] = a2.x * mv; xm[lr][lc + 9] = a2.y * mv; xm[lr][lc + 10] = a2.z * mv; xm[lr][lc + 11] = a2.w * mv;
            xm[lr][lc + 12] = a3.x * mv; xm[lr][lc + 13] = a3.y * mv; xm[lr][lc + 14] = a3.z * mv; xm[lr][lc + 15] = a3.w * mv;
        }
        __syncthreads();
#pragma unroll 4
        for (int nn = 0; nn < 32; nn++) {
            float4 e0 = *(const float4*)&ev[nn][ty * 4];
            float4 e1 = *(const float4*)&ev[nn][64 + ty * 4];
            float4 x0 = *(const float4*)&xm[nn][tx * 4];
            float4 x1 = *(const float4*)&xm[nn][64 + tx * 4];
            float ee[8] = {e0.x, e0.y, e0.z, e0.w, e1.x, e1.y, e1.z, e1.w};
            float xx[8] = {x0.x, x0.y, x0.z, x0.w, x1.x, x1.y, x1.z, x1.w};
#pragma unroll
            for (int i = 0; i < 8; i++)
#pragma unroll
                for (int j = 0; j < 8; j++) acc[i][j] += ee[i] * xx[j];
        }
        __syncthreads();
    }
    float* dst = part + ((size_t)b * NCH + nch) * (Kn * Cn);
#pragma unroll
    for (int i = 0; i < 8; i++) {
        const int k = (i < 4) ? (ty * 4 + i) : (64 + ty * 4 + i - 4);
        *(float4*)(dst + (size_t)k * Cn + c0 + tx * 4) =
            make_float4(acc[i][0], acc[i][1], acc[i][2], acc[i][3]);
        *(float4*)(dst + (size_t)k * Cn + c0 + 64 + tx * 4) =
            make_float4(acc[i][4], acc[i][5], acc[i][6], acc[i][7]);
    }
}

// ---------------------------------------------------------------------------
// Reduce chunk partials and apply heat coefficient exp(-eval * t_c)
// ---------------------------------------------------------------------------
__global__ __launch_bounds__(256) void k_reduce(
    const float* __restrict__ part, int nchunks,
    const float* __restrict__ evals, const float* __restrict__ tvec,
    float* __restrict__ spec)
{
    const int b = blockIdx.x >> 7, k = blockIdx.x & 127, c = threadIdx.x;
    float ssum = 0.f;
    const float* p = part + ((size_t)b * nchunks * Kn + k) * Cn + c;
    for (int j = 0; j < nchunks; j++) ssum += p[(size_t)j * Kn * Cn];
    const float lam = evals[b * Kn + k];
    const float tt = fmaxf(tvec[c], 1e-8f);
    spec[((size_t)b * Kn + k) * Cn + c] = ssum * __expf(-lam * tt);
}

// ---------------------------------------------------------------------------
// Gather evecs & mass at far indices
// ---------------------------------------------------------------------------
__global__ __launch_bounds__(128) void k_gather(
    const float* __restrict__ evecs, const float* __restrict__ mass,
    const int* __restrict__ far, float* __restrict__ evf, float* __restrict__ massf)
{
    const int row = blockIdx.x;  // b*M + m
    const int b = row >> 10;
    const int idx = far[row];
    const int t = threadIdx.x;
    evf[(size_t)row * Kn + t] = evecs[((size_t)b * Nn + idx) * Kn + t];
    if (t == 0) massf[row] = mass[(size_t)b * Nn + idx];
}

// ---------------------------------------------------------------------------
// Generic 64x64-tile GEMM: out[row][c'] = X[row][0:KD] @ W[KD][256] (+bias)(*mass)
// ---------------------------------------------------------------------------
struct G3 {
    const float* W[3];
    const float* bias[3];
    float* out[3];
};

template<int KD, bool PERB, bool MMASS>
__global__ __launch_bounds__(256) void k_gemm64(
    const float* __restrict__ X, G3 g, const float* __restrict__ massf)
{
    const int mt = blockIdx.x, ct = blockIdx.y, z = blockIdx.z;
    const int row0 = mt * 64, c0 = ct * 64;
    const int b = row0 >> 10;
    const float* Wp = g.W[z];
    const float* bias = g.bias[z];
    float* out = g.out[z];
    const size_t woff = PERB ? (size_t)b * KD * 256 : 0;

    __shared__ float xT[32][68];   // 68*4 = 272 B rows (16B-aligned)
    __shared__ float wl[32][64];
    const int t = threadIdx.x, tx = t & 15, ty = t >> 4;
    float acc[4][4] = {};

    for (int k0 = 0; k0 < KD; k0 += 32) {
        {
            const int m = t >> 2, cc0 = (t & 3) * 8;
            const float* xs = X + (size_t)(row0 + m) * KD + k0 + cc0;
            float4 a0 = *(const float4*)xs, a1 = *(const float4*)(xs + 4);
            xT[cc0 + 0][m] = a0.x; xT[cc0 + 1][m] = a0.y; xT[cc0 + 2][m] = a0.z; xT[cc0 + 3][m] = a0.w;
            xT[cc0 + 4][m] = a1.x; xT[cc0 + 5][m] = a1.y; xT[cc0 + 6][m] = a1.z; xT[cc0 + 7][m] = a1.w;
        }
        {
            const int cc = t >> 3, col = (t & 7) * 8;
            const float* wsrc = Wp + woff + (size_t)(k0 + cc) * 256 + c0 + col;
            float4 a0 = *(const float4*)wsrc, a1 = *(const float4*)(wsrc + 4);
            wl[cc][col + 0] = a0.x; wl[cc][col + 1] = a0.y; wl[cc][col + 2] = a0.z; wl[cc][col + 3] = a0.w;
            wl[cc][col + 4] = a1.x; wl[cc][col + 5] = a1.y; wl[cc][col + 6] = a1.z; wl[cc][col + 7] = a1.w;
        }
        __syncthreads();
#pragma unroll 8
        for (int cc = 0; cc < 32; cc++) {
            float4 xv = *(const float4*)&xT[cc][ty * 4];
            float4 wv = *(const float4*)&wl[cc][tx * 4];
            float xa[4] = {xv.x, xv.y, xv.z, xv.w};
            float wa[4] = {wv.x, wv.y, wv.z, wv.w};
#pragma unroll
            for (int i = 0; i < 4; i++)
#pragma unroll
                for (int j = 0; j < 4; j++) acc[i][j] += xa[i] * wa[j];
        }
        __syncthreads();
    }
    float bj[4] = {0.f, 0.f, 0.f, 0.f};
    if (bias) {
#pragma unroll
        for (int j = 0; j < 4; j++) bj[j] = bias[c0 + tx * 4 + j];
    }
#pragma unroll
    for (int i = 0; i < 4; i++) {
        const int row = row0 + ty * 4 + i;
        const float mm = MMASS ? massf[row] : 1.f;
        *(float4*)(out + (size_t)row * 256 + c0 + tx * 4) =
            make_float4((acc[i][0] + bj[0]) * mm, (acc[i][1] + bj[1]) * mm,
                        (acc[i][2] + bj[2]) * mm, (acc[i][3] + bj[3]) * mm);
    }
}

// ---------------------------------------------------------------------------
// GroupNorm stats: per (b, g) mean/invstd over M x 8 channels
// ---------------------------------------------------------------------------
__global__ __launch_bounds__(256) void k_gnstats(const float* __restrict__ xfar, float* __restrict__ gst)
{
    const int b = blockIdx.x >> 5, g = blockIdx.x & 31;
    const int t = threadIdx.x;
    float s = 0.f, s2 = 0.f;
#pragma unroll
    for (int i = 0; i < 4; i++) {
        const int m = t * 4 + i;
        const float* p = xfar + ((size_t)b * Mn + m) * Cn + g * 8;
        float4 a = *(const float4*)p;
        float4 c = *(const float4*)(p + 4);
        s += a.x + a.y + a.z + a.w + c.x + c.y + c.z + c.w;
        s2 += a.x * a.x + a.y * a.y + a.z * a.z + a.w * a.w +
              c.x * c.x + c.y * c.y + c.z * c.z + c.w * c.w;
    }
    __shared__ float sb[256], sb2[256];
    sb[t] = s; sb2[t] = s2;
    __syncthreads();
    for (int o = 128; o > 0; o >>= 1) {
        if (t < o) { sb[t] += sb[t + o]; sb2[t] += sb2[t + o]; }
        __syncthreads();
    }
    if (t == 0) {
        const float mean = sb[0] * (1.f / 8192.f);
        const float var = sb2[0] * (1.f / 8192.f) - mean * mean;
        gst[2 * blockIdx.x] = mean;
        gst[2 * blockIdx.x + 1] = rsqrtf(var + 1e-6f);
    }
}

__global__ __launch_bounds__(256) void k_gnapply(
    const float* __restrict__ xfar, const float* __restrict__ gst,
    const float* __restrict__ gw, const float* __restrict__ gb, float* __restrict__ xn)
{
    const int idx = (blockIdx.x * 256 + threadIdx.x) * 4;
    const int c = idx & 255;
    const int row = idx >> 8;
    const int b = row >> 10;
    const int g = c >> 3;
    const float2 st = *(const float2*)&gst[2 * (b * 32 + g)];
    float4 vv = *(const float4*)&xfar[idx];
    float4 w4 = *(const float4*)&gw[c];
    float4 b4 = *(const float4*)&gb[c];
    float4 o;
    o.x = (vv.x - st.x) * st.y * w4.x + b4.x;
    o.y = (vv.y - st.x) * st.y * w4.y + b4.y;
    o.z = (vv.z - st.x) * st.y * w4.z + b4.z;
    o.w = (vv.w - st.x) * st.y * w4.w + b4.w;
    *(float4*)&xn[idx] = o;
}

// ---------------------------------------------------------------------------
// Attention: K-split flash. One thread per q-row; seg = 256 keys.
// FULLY unrolled j-loops: keeps s[32]/acc[32]/qr[32] in VGPRs (round-2's
// partial unroll left j dynamic -> scratch spill -> 165 us).
// ---------------------------------------------------------------------------
__global__ __launch_bounds__(256) void k_attn(
    const float* __restrict__ q, const float* __restrict__ kbuf, const float* __restrict__ vbuf,
    float* __restrict__ pacc, float* __restrict__ pm, float* __restrict__ pl)
{
    const int qt = blockIdx.x, seg = blockIdx.y, bh = blockIdx.z;
    const int b = bh >> 3, h = bh & 7;
    const int t = threadIdx.x;
    const int m = qt * 256 + t;
    __shared__ float kl[32][40];
    __shared__ float vl[32][40];
    float qr[32];
    const float* qp = q + ((size_t)b * Mn + m) * Cn + h * Dn;
#pragma unroll
    for (int i = 0; i < 32; i += 4) {
        float4 a = *(const float4*)(qp + i);
        qr[i] = a.x; qr[i + 1] = a.y; qr[i + 2] = a.z; qr[i + 3] = a.w;
    }
    float mx = -1e30f, l = 0.f;
    float acc[32] = {};
    const float scale = 0.17677669529663687f;  // 1/sqrt(32)
    const int lr = t >> 3, lc = (t & 7) * 4;
    for (int k0 = seg * 256; k0 < seg * 256 + 256; k0 += 32) {
        {
            const size_t krow = ((size_t)b * Mn + k0 + lr) * Cn + h * Dn + lc;
            float4 a = *(const float4*)(kbuf + krow);
            kl[lr][lc] = a.x; kl[lr][lc + 1] = a.y; kl[lr][lc + 2] = a.z; kl[lr][lc + 3] = a.w;
            float4 bv4 = *(const float4*)(vbuf + krow);
            vl[lr][lc] = bv4.x; vl[lr][lc + 1] = bv4.y; vl[lr][lc + 2] = bv4.z; vl[lr][lc + 3] = bv4.w;
        }
        __syncthreads();
        float s[32];
#pragma unroll
        for (int j = 0; j < 32; j++) {
            float d = 0.f;
#pragma unroll
            for (int i = 0; i < 32; i += 4) {
                float4 a = *(const float4*)&kl[j][i];
                d += qr[i] * a.x + qr[i + 1] * a.y + qr[i + 2] * a.z + qr[i + 3] * a.w;
            }
            s[j] = d * scale;
        }
        float tm = mx;
#pragma unroll
        for (int j = 0; j < 32; j++) tm = fmaxf(tm, s[j]);
        const float r = __expf(mx - tm);
        l *= r;
#pragma unroll
        for (int i = 0; i < 32; i++) acc[i] *= r;
#pragma unroll
        for (int j = 0; j < 32; j++) {
            const float p = __expf(s[j] - tm);
            l += p;
#pragma unroll
            for (int i = 0; i < 32; i += 4) {
                float4 a = *(const float4*)&vl[j][i];
                acc[i] += p * a.x; acc[i + 1] += p * a.y; acc[i + 2] += p * a.z; acc[i + 3] += p * a.w;
            }
        }
        mx = tm;
        __syncthreads();
    }
    const size_t pr = (((size_t)seg * Bn + b) * Hn + h) * Mn + m;
    pm[pr] = mx; pl[pr] = l;
    float* pa = pacc + pr * 32;
#pragma unroll
    for (int i = 0; i < 32; i += 4)
        *(float4*)(pa + i) = make_float4(acc[i], acc[i + 1], acc[i + 2], acc[i + 3]);
}

__global__ __launch_bounds__(256) void k_comb(
    const float* __restrict__ pacc, const float* __restrict__ pm, const float* __restrict__ pl,
    float* __restrict__ att)
{
    const int t = threadIdx.x;
    const size_t row = (size_t)blockIdx.x * 8 + (t >> 5);  // (b*8+h)*1024 + m
    const int j = t & 31;
    float M = -1e30f;
#pragma unroll
    for (int s = 0; s < 4; s++) M = fmaxf(M, pm[(size_t)s * 32768 + row]);
    float L = 0.f, a = 0.f;
#pragma unroll
    for (int s = 0; s < 4; s++) {
        const float w = __expf(pm[(size_t)s * 32768 + row] - M);
        L += w * pl[(size_t)s * 32768 + row];
        a += w * pacc[((size_t)s * 32768 + row) * 32 + j];
    }
    const int bh = (int)(row >> 10);
    const int mrow = (int)(row & 1023);
    const int b = bh >> 3, h = bh & 7;
    att[((size_t)b * Mn + mrow) * Cn + h * 32 + j] = a / L;
}

// ---------------------------------------------------------------------------
// to_basis #2 over far rows only
// ---------------------------------------------------------------------------
__global__ __launch_bounds__(256) void k_tobasis2(
    const float* __restrict__ evf, const float* __restrict__ xo, float* __restrict__ part)
{
    const int mch = blockIdx.x, ct = blockIdx.y, b = blockIdx.z;
    const int m0 = mch * (Mn / MCH);
    const int c0 = ct * 128;
    __shared__ float ev[32][128];
    __shared__ float xm[32][128];
    const int t = threadIdx.x, tx = t & 15, ty = t >> 4;
    float acc[8][8];
#pragma unroll
    for (int i = 0; i < 8; i++)
#pragma unroll
        for (int j = 0; j < 8; j++) acc[i][j] = 0.f;
    const int lr = t >> 3, lc = (t & 7) * 16;
    for (int s = 0; s < Mn / MCH; s += 32) {
        const size_t mrow = (size_t)b * Mn + m0 + s + lr;
        {
            const float* es = evf + mrow * Kn + lc;
            *(float4*)&ev[lr][lc]      = *(const float4*)es;
            *(float4*)&ev[lr][lc + 4]  = *(const float4*)(es + 4);
            *(float4*)&ev[lr][lc + 8]  = *(const float4*)(es + 8);
            *(float4*)&ev[lr][lc + 12] = *(const float4*)(es + 12);
            const float* xs = xo + mrow * Cn + c0 + lc;
            *(float4*)&xm[lr][lc]      = *(const float4*)xs;
            *(float4*)&xm[lr][lc + 4]  = *(const float4*)(xs + 4);
            *(float4*)&xm[lr][lc + 8]  = *(const float4*)(xs + 8);
            *(float4*)&xm[lr][lc + 12] = *(const float4*)(xs + 12);
        }
        __syncthreads();
#pragma unroll 4
        for (int nn = 0; nn < 32; nn++) {
            float4 e0 = *(const float4*)&ev[nn][ty * 4];
            float4 e1 = *(const float4*)&ev[nn][64 + ty * 4];
            float4 x0 = *(const float4*)&xm[nn][tx * 4];
            float4 x1 = *(const float4*)&xm[nn][64 + tx * 4];
            float ee[8] = {e0.x, e0.y, e0.z, e0.w, e1.x, e1.y, e1.z, e1.w};
            float xx[8] = {x0.x, x0.y, x0.z, x0.w, x1.x, x1.y, x1.z, x1.w};
#pragma unroll
            for (int i = 0; i < 8; i++)
#pragma unroll
                for (int j = 0; j < 8; j++) acc[i][j] += ee[i] * xx[j];
        }
        __syncthreads();
    }
    float* dst = part + ((size_t)b * MCH + mch) * (Kn * Cn);
#pragma unroll
    for (int i = 0; i < 8; i++) {
        const int k = (i < 4) ? (ty * 4 + i) : (64 + ty * 4 + i - 4);
        *(float4*)(dst + (size_t)k * Cn + c0 + tx * 4) =
            make_float4(acc[i][0], acc[i][1], acc[i][2], acc[i][3]);
        *(float4*)(dst + (size_t)k * Cn + c0 + 64 + tx * 4) =
            make_float4(acc[i][4], acc[i][5], acc[i][6], acc[i][7]);
    }
}

// ---------------------------------------------------------------------------
// from_basis #2: out[b,n,c] = out_w[c] * sum_k evecs[b,n,k]*spec2'[b,k,c]
// ---------------------------------------------------------------------------
__global__ __launch_bounds__(256) void k_frombasis2(
    const float* __restrict__ evecs, const float* __restrict__ spec,
    const float* __restrict__ outw, float* __restrict__ out)
{
    const int nt = blockIdx.x, ct = blockIdx.y, b = blockIdx.z;
    const int n0 = nt * 128, c0 = ct * 128;
    __shared__ float evT[32][132];
    __shared__ float sp[32][128];
    const int t = threadIdx.x, tx = t & 15, ty = t >> 4;
    float acc[8][8];
#pragma unroll
    for (int i = 0; i < 8; i++)
#pragma unroll
        for (int j = 0; j < 8; j++) acc[i][j] = 0.f;
    const int en = t >> 1, ek0 = (t & 1) * 16;
    const int sr = t >> 3, sc = (t & 7) * 16;
    for (int k0 = 0; k0 < Kn; k0 += 32) {
        {
            const float* es = evecs + ((size_t)b * Nn + n0 + en) * Kn + k0 + ek0;
            float4 a0 = *(const float4*)es, a1 = *(const float4*)(es + 4);
            float4 a2 = *(const float4*)(es + 8), a3 = *(const float4*)(es + 12);
            evT[ek0 + 0][en] = a0.x; evT[ek0 + 1][en] = a0.y; evT[ek0 + 2][en] = a0.z; evT[ek0 + 3][en] = a0.w;
            evT[ek0 + 4][en] = a1.x; evT[ek0 + 5][en] = a1.y; evT[ek0 + 6][en] = a1.z; evT[ek0 + 7][en] = a1.w;
            evT[ek0 + 8][en] = a2.x; evT[ek0 + 9][en] = a2.y; evT[ek0 + 10][en] = a2.z; evT[ek0 + 11][en] = a2.w;
            evT[ek0 + 12][en] = a3.x; evT[ek0 + 13][en] = a3.y; evT[ek0 + 14][en] = a3.z; evT[ek0 + 15][en] = a3.w;
            const float* ss = spec + ((size_t)b * Kn + k0 + sr) * Cn + c0 + sc;
            *(float4*)&sp[sr][sc]      = *(const float4*)ss;
            *(float4*)&sp[sr][sc + 4]  = *(const float4*)(ss + 4);
            *(float4*)&sp[sr][sc + 8]  = *(const float4*)(ss + 8);
            *(float4*)&sp[sr][sc + 12] = *(const float4*)(ss + 12);
        }
        __syncthreads();
#pragma unroll 4
        for (int kk2 = 0; kk2 < 32; kk2++) {
            float4 e0 = *(const float4*)&evT[kk2][ty * 4];
            float4 e1 = *(const float4*)&evT[kk2][64 + ty * 4];
            float4 s0 = *(const float4*)&sp[kk2][tx * 4];
            float4 s1 = *(const float4*)&sp[kk2][64 + tx * 4];
            float ee[8] = {e0.x, e0.y, e0.z, e0.w, e1.x, e1.y, e1.z, e1.w};
            float sv[8] = {s0.x, s0.y, s0.z, s0.w, s1.x, s1.y, s1.z, s1.w};
#pragma unroll
            for (int i = 0; i < 8; i++)
#pragma unroll
                for (int j = 0; j < 8; j++) acc[i][j] += ee[i] * sv[j];
        }
        __syncthreads();
    }
    float ow[8];
#pragma unroll
    for (int j = 0; j < 8; j++) {
        const int c = c0 + ((j < 4) ? (tx * 4 + j) : (64 + tx * 4 + j - 4));
        ow[j] = fmaxf(outw[c], 1e-8f);
    }
#pragma unroll
    for (int i = 0; i < 8; i++) {
        const int n = n0 + ((i < 4) ? (ty * 4 + i) : (64 + ty * 4 + i - 4));
        float* od = out + ((size_t)b * Nn + n) * Cn + c0;
        *(float4*)(od + tx * 4) =
            make_float4(acc[i][0] * ow[0], acc[i][1] * ow[1], acc[i][2] * ow[2], acc[i][3] * ow[3]);
        *(float4*)(od + 64 + tx * 4) =
            make_float4(acc[i][4] * ow[4], acc[i][5] * ow[5], acc[i][6] * ow[6], acc[i][7] * ow[7]);
    }
}

// ---------------------------------------------------------------------------
extern "C" void kernel_launch(void* const* d_in, const int* in_sizes, int n_in,
                              void* d_out, int out_size, void* d_ws, size_t ws_size,
                              hipStream_t stream)
{
    const float* x     = (const float*)d_in[0];
    const float* mass  = (const float*)d_in[1];
    const float* evals = (const float*)d_in[2];
    const float* evecs = (const float*)d_in[3];
    const int*   far   = (const int*)d_in[4];
    const float* t_in  = (const float*)d_in[5];
    const float* t_out = (const float*)d_in[6];
    const float* gn_w  = (const float*)d_in[7];
    const float* gn_b  = (const float*)d_in[8];
    const float* Wq    = (const float*)d_in[9];
    const float* bq    = (const float*)d_in[10];
    const float* Wk    = (const float*)d_in[11];
    const float* bk    = (const float*)d_in[12];
    const float* Wv    = (const float*)d_in[13];
    const float* bv    = (const float*)d_in[14];
    const float* Wo    = (const float*)d_in[15];
    const float* bo    = (const float*)d_in[16];
    const float* outw  = (const float*)d_in[17];
    float* out = (float*)d_out;
    float* ws = (float*)d_ws;

    // workspace layout (floats); region A is reused: part1 -> pacc -> part2
    float* A     = ws;               // 8,388,608
    float* spec1 = ws + 8388608;     // 131,072
    float* evf   = spec1 + 131072;   // 524,288
    float* massf = evf + 524288;     // 4,096
    float* xfar  = massf + 4096;     // 1,048,576
    float* gst   = xfar + 1048576;   // 256
    float* xn    = gst + 256;        // 1,048,576
    float* q     = xn + 1048576;     // 1,048,576
    float* kk    = q + 1048576;      // 1,048,576
    float* v     = kk + 1048576;     // 1,048,576
    float* pm    = v + 1048576;      // 131,072
    float* pl    = pm + 131072;      // 131,072
    float* att   = pl + 131072;      // 1,048,576
    float* xo    = att + 1048576;    // 1,048,576
    float* spec2 = xo + 1048576;     // 131,072
    float* pacc  = A;                // alias: part1 dead after k_reduce
    float* part2 = A;                // alias: pacc dead after k_comb

    k_tobasis1<<<dim3(NCH, 2, Bn), 256, 0, stream>>>(x, mass, evecs, A);
    k_reduce<<<Bn * Kn, Cn, 0, stream>>>(A, NCH, evals, t_in, spec1);
    k_gather<<<Bn * Mn, Kn, 0, stream>>>(evecs, mass, far, evf, massf);
    {
        G3 g{};
        g.W[0] = spec1; g.bias[0] = nullptr; g.out[0] = xfar;
        k_gemm64<128, true, false><<<dim3(64, 4, 1), 256, 0, stream>>>(evf, g, nullptr);
    }
    k_gnstats<<<Bn * 32, 256, 0, stream>>>(xfar, gst);
    k_gnapply<<<1024, 256, 0, stream>>>(xfar, gst, gn_w, gn_b, xn);
    {
        G3 g{};
        g.W[0] = Wq; g.W[1] = Wk; g.W[2] = Wv;
        g.bias[0] = bq; g.bias[1] = bk; g.bias[2] = bv;
        g.out[0] = q; g.out[1] = kk; g.out[2] = v;
        k_gemm64<256, false, false><<<dim3(64, 4, 3), 256, 0, stream>>>(xn, g, nullptr);
    }
    k_attn<<<dim3(4, 4, 32), 256, 0, stream>>>(q, kk, v, pacc, pm, pl);
    k_comb<<<4096, 256, 0, stream>>>(pacc, pm, pl, att);
    {
        G3 g{};
        g.W[0] = Wo; g.bias[0] = bo; g.out[0] = xo;
        k_gemm64<256, false, true><<<dim3(64, 4, 1), 256, 0, stream>>>(att, g, massf);
    }
    k_tobasis2<<<dim3(MCH, 2, Bn), 256, 0, stream>>>(evf, xo, part2);
    k_reduce<<<Bn * Kn, Cn, 0, stream>>>(part2, MCH, evals, t_out, spec2);
    k_frombasis2<<<dim3(256, 2, Bn), 256, 0, stream>>>(evecs, spec2, outw, out);
}

// Round 5
// 643.852 us; speedup vs baseline: 1.1739x; 1.0863x over previous
//
#include <hip/hip_runtime.h>
#include <hip/hip_bf16.h>

// All inputs and the output are fp32 (established empirically in rounds 1-2).
// Round-4 post-timing divergence traced to workspace overflow (~68 MB used vs
// ~64 MiB available): OOB writes corrupted neighboring allocations (pristine
// input copies), so replays after timing diverged. This round: lifetime-based
// aliasing shrinks the high-water mark to 56.5 MiB. No kernel changes.

#define Bn 4
#define Nn 32768
#define Kn 128
#define Cn 256
#define Mn 1024
#define Hn 8
#define Dn 32
#define NCH 64   // n-chunks for to_basis1 (chunk = 512 rows)
#define MCH 16   // m-chunks for to_basis2 (chunk = 64 rows)
#define SEG 8    // key segments in flash attention (128 keys each)

// ---------------------------------------------------------------------------
// K1: to_basis #1.  part[b][nch][k][c] = sum_{n in chunk} evecs[b,n,k] * x[b,n,c]*mass[b,n]
// ---------------------------------------------------------------------------
__global__ __launch_bounds__(256) void k_tobasis1(
    const float* __restrict__ x, const float* __restrict__ mass,
    const float* __restrict__ evecs, float* __restrict__ part)
{
    const int nch = blockIdx.x, ct = blockIdx.y, b = blockIdx.z;
    const int n0 = nch * (Nn / NCH);
    const int c0 = ct * 128;
    __shared__ float ev[32][128];
    __shared__ float xm[32][128];
    const int t = threadIdx.x, tx = t & 15, ty = t >> 4;
    float acc[8][8];
#pragma unroll
    for (int i = 0; i < 8; i++)
#pragma unroll
        for (int j = 0; j < 8; j++) acc[i][j] = 0.f;

    const int lr = t >> 3;        // 0..31
    const int lc = (t & 7) * 16;  // 0..112
    for (int s = 0; s < Nn / NCH; s += 32) {
        const size_t nrow = (size_t)b * Nn + n0 + s + lr;
        {
            const float* es = evecs + nrow * Kn + lc;
            *(float4*)&ev[lr][lc]      = *(const float4*)es;
            *(float4*)&ev[lr][lc + 4]  = *(const float4*)(es + 4);
            *(float4*)&ev[lr][lc + 8]  = *(const float4*)(es + 8);
            *(float4*)&ev[lr][lc + 12] = *(const float4*)(es + 12);
            const float mv = mass[nrow];
            const float* xs = x + nrow * Cn + c0 + lc;
            float4 a0 = *(const float4*)xs, a1 = *(const float4*)(xs + 4);
            float4 a2 = *(const float4*)(xs + 8), a3 = *(const float4*)(xs + 12);
            xm[lr][lc + 0] = a0.x * mv; xm[lr][lc + 1] = a0.y * mv; xm[lr][lc + 2] = a0.z * mv; xm[lr][lc + 3] = a0.w * mv;
            xm[lr][lc + 4] = a1.x * mv; xm[lr][lc + 5] = a1.y * mv; xm[lr][lc + 6] = a1.z * mv; xm[lr][lc + 7] = a1.w * mv;
            xm[lr][lc + 8] = a2.x * mv; xm[lr][lc + 9] = a2.y * mv; xm[lr][lc + 10] = a2.z * mv; xm[lr][lc + 11] = a2.w * mv;
            xm[lr][lc + 12] = a3.x * mv; xm[lr][lc + 13] = a3.y * mv; xm[lr][lc + 14] = a3.z * mv; xm[lr][lc + 15] = a3.w * mv;
        }
        __syncthreads();
#pragma unroll 4
        for (int nn = 0; nn < 32; nn++) {
            float4 e0 = *(const float4*)&ev[nn][ty * 4];
            float4 e1 = *(const float4*)&ev[nn][64 + ty * 4];
            float4 x0 = *(const float4*)&xm[nn][tx * 4];
            float4 x1 = *(const float4*)&xm[nn][64 + tx * 4];
            float ee[8] = {e0.x, e0.y, e0.z, e0.w, e1.x, e1.y, e1.z, e1.w};
            float xx[8] = {x0.x, x0.y, x0.z, x0.w, x1.x, x1.y, x1.z, x1.w};
#pragma unroll
            for (int i = 0; i < 8; i++)
#pragma unroll
                for (int j = 0; j < 8; j++) acc[i][j] += ee[i] * xx[j];
        }
        __syncthreads();
    }
    float* dst = part + ((size_t)b * NCH + nch) * (Kn * Cn);
#pragma unroll
    for (int i = 0; i < 8; i++) {
        const int k = (i < 4) ? (ty * 4 + i) : (64 + ty * 4 + i - 4);
        *(float4*)(dst + (size_t)k * Cn + c0 + tx * 4) =
            make_float4(acc[i][0], acc[i][1], acc[i][2], acc[i][3]);
        *(float4*)(dst + (size_t)k * Cn + c0 + 64 + tx * 4) =
            make_float4(acc[i][4], acc[i][5], acc[i][6], acc[i][7]);
    }
}

// ---------------------------------------------------------------------------
// Reduce chunk partials and apply heat coefficient exp(-eval * t_c)
// ---------------------------------------------------------------------------
__global__ __launch_bounds__(256) void k_reduce(
    const float* __restrict__ part, int nchunks,
    const float* __restrict__ evals, const float* __restrict__ tvec,
    float* __restrict__ spec)
{
    const int b = blockIdx.x >> 7, k = blockIdx.x & 127, c = threadIdx.x;
    float ssum = 0.f;
    const float* p = part + ((size_t)b * nchunks * Kn + k) * Cn + c;
    for (int j = 0; j < nchunks; j++) ssum += p[(size_t)j * Kn * Cn];
    const float lam = evals[b * Kn + k];
    const float tt = fmaxf(tvec[c], 1e-8f);
    spec[((size_t)b * Kn + k) * Cn + c] = ssum * __expf(-lam * tt);
}

// ---------------------------------------------------------------------------
// Gather evecs & mass at far indices
// ---------------------------------------------------------------------------
__global__ __launch_bounds__(128) void k_gather(
    const float* __restrict__ evecs, const float* __restrict__ mass,
    const int* __restrict__ far, float* __restrict__ evf, float* __restrict__ massf)
{
    const int row = blockIdx.x;  // b*M + m
    const int b = row >> 10;
    const int idx = far[row];
    const int t = threadIdx.x;
    evf[(size_t)row * Kn + t] = evecs[((size_t)b * Nn + idx) * Kn + t];
    if (t == 0) massf[row] = mass[(size_t)b * Nn + idx];
}

// ---------------------------------------------------------------------------
// Generic 64x64-tile GEMM: out[row][c'] = X[row][0:KD] @ W[KD][256] (+bias)(*mass)
// ---------------------------------------------------------------------------
struct G3 {
    const float* W[3];
    const float* bias[3];
    float* out[3];
};

template<int KD, bool PERB, bool MMASS>
__global__ __launch_bounds__(256) void k_gemm64(
    const float* __restrict__ X, G3 g, const float* __restrict__ massf)
{
    const int mt = blockIdx.x, ct = blockIdx.y, z = blockIdx.z;
    const int row0 = mt * 64, c0 = ct * 64;
    const int b = row0 >> 10;
    const float* Wp = g.W[z];
    const float* bias = g.bias[z];
    float* out = g.out[z];
    const size_t woff = PERB ? (size_t)b * KD * 256 : 0;

    __shared__ float xT[32][68];   // 68*4 = 272 B rows (16B-aligned)
    __shared__ float wl[32][64];
    const int t = threadIdx.x, tx = t & 15, ty = t >> 4;
    float acc[4][4] = {};

    for (int k0 = 0; k0 < KD; k0 += 32) {
        {
            const int m = t >> 2, cc0 = (t & 3) * 8;
            const float* xs = X + (size_t)(row0 + m) * KD + k0 + cc0;
            float4 a0 = *(const float4*)xs, a1 = *(const float4*)(xs + 4);
            xT[cc0 + 0][m] = a0.x; xT[cc0 + 1][m] = a0.y; xT[cc0 + 2][m] = a0.z; xT[cc0 + 3][m] = a0.w;
            xT[cc0 + 4][m] = a1.x; xT[cc0 + 5][m] = a1.y; xT[cc0 + 6][m] = a1.z; xT[cc0 + 7][m] = a1.w;
        }
        {
            const int cc = t >> 3, col = (t & 7) * 8;
            const float* wsrc = Wp + woff + (size_t)(k0 + cc) * 256 + c0 + col;
            float4 a0 = *(const float4*)wsrc, a1 = *(const float4*)(wsrc + 4);
            wl[cc][col + 0] = a0.x; wl[cc][col + 1] = a0.y; wl[cc][col + 2] = a0.z; wl[cc][col + 3] = a0.w;
            wl[cc][col + 4] = a1.x; wl[cc][col + 5] = a1.y; wl[cc][col + 6] = a1.z; wl[cc][col + 7] = a1.w;
        }
        __syncthreads();
#pragma unroll 8
        for (int cc = 0; cc < 32; cc++) {
            float4 xv = *(const float4*)&xT[cc][ty * 4];
            float4 wv = *(const float4*)&wl[cc][tx * 4];
            float xa[4] = {xv.x, xv.y, xv.z, xv.w};
            float wa[4] = {wv.x, wv.y, wv.z, wv.w};
#pragma unroll
            for (int i = 0; i < 4; i++)
#pragma unroll
                for (int j = 0; j < 4; j++) acc[i][j] += xa[i] * wa[j];
        }
        __syncthreads();
    }
    float bj[4] = {0.f, 0.f, 0.f, 0.f};
    if (bias) {
#pragma unroll
        for (int j = 0; j < 4; j++) bj[j] = bias[c0 + tx * 4 + j];
    }
#pragma unroll
    for (int i = 0; i < 4; i++) {
        const int row = row0 + ty * 4 + i;
        const float mm = MMASS ? massf[row] : 1.f;
        *(float4*)(out + (size_t)row * 256 + c0 + tx * 4) =
            make_float4((acc[i][0] + bj[0]) * mm, (acc[i][1] + bj[1]) * mm,
                        (acc[i][2] + bj[2]) * mm, (acc[i][3] + bj[3]) * mm);
    }
}

// ---------------------------------------------------------------------------
// GroupNorm stats: per (b, g) mean/invstd over M x 8 channels
// ---------------------------------------------------------------------------
__global__ __launch_bounds__(256) void k_gnstats(const float* __restrict__ xfar, float* __restrict__ gst)
{
    const int b = blockIdx.x >> 5, g = blockIdx.x & 31;
    const int t = threadIdx.x;
    float s = 0.f, s2 = 0.f;
#pragma unroll
    for (int i = 0; i < 4; i++) {
        const int m = t * 4 + i;
        const float* p = xfar + ((size_t)b * Mn + m) * Cn + g * 8;
        float4 a = *(const float4*)p;
        float4 c = *(const float4*)(p + 4);
        s += a.x + a.y + a.z + a.w + c.x + c.y + c.z + c.w;
        s2 += a.x * a.x + a.y * a.y + a.z * a.z + a.w * a.w +
              c.x * c.x + c.y * c.y + c.z * c.z + c.w * c.w;
    }
    __shared__ float sb[256], sb2[256];
    sb[t] = s; sb2[t] = s2;
    __syncthreads();
    for (int o = 128; o > 0; o >>= 1) {
        if (t < o) { sb[t] += sb[t + o]; sb2[t] += sb2[t + o]; }
        __syncthreads();
    }
    if (t == 0) {
        const float mean = sb[0] * (1.f / 8192.f);
        const float var = sb2[0] * (1.f / 8192.f) - mean * mean;
        gst[2 * blockIdx.x] = mean;
        gst[2 * blockIdx.x + 1] = rsqrtf(var + 1e-6f);
    }
}

__global__ __launch_bounds__(256) void k_gnapply(
    const float* __restrict__ xfar, const float* __restrict__ gst,
    const float* __restrict__ gw, const float* __restrict__ gb, float* __restrict__ xn)
{
    const int idx = (blockIdx.x * 256 + threadIdx.x) * 4;
    const int c = idx & 255;
    const int row = idx >> 8;
    const int b = row >> 10;
    const int g = c >> 3;
    const float2 st = *(const float2*)&gst[2 * (b * 32 + g)];
    float4 vv = *(const float4*)&xfar[idx];
    float4 w4 = *(const float4*)&gw[c];
    float4 b4 = *(const float4*)&gb[c];
    float4 o;
    o.x = (vv.x - st.x) * st.y * w4.x + b4.x;
    o.y = (vv.y - st.x) * st.y * w4.y + b4.y;
    o.z = (vv.z - st.x) * st.y * w4.z + b4.z;
    o.w = (vv.w - st.x) * st.y * w4.w + b4.w;
    *(float4*)&xn[idx] = o;
}

// ---------------------------------------------------------------------------
// Flash attention, outer-product tiles (64 q x 128 keys per block).
// ---------------------------------------------------------------------------
__global__ __launch_bounds__(256) void k_attn(
    const float* __restrict__ q, const float* __restrict__ kbuf, const float* __restrict__ vbuf,
    float* __restrict__ pacc, float* __restrict__ pm, float* __restrict__ pl)
{
    const int qt = blockIdx.x;      // 16 tiles of 64 q-rows
    const int seg = blockIdx.y;     // SEG segs of 128 keys
    const int bh = blockIdx.z;
    const int b = bh >> 3, h = bh & 7;
    const int t = threadIdx.x;
    const int tx = t & 15, ty = t >> 4;

    __shared__ float qT[32][68];    // [d][q-row]
    __shared__ float kT[32][68];    // [d][key]
    __shared__ float vsm[64][36];   // [key][d]
    __shared__ float psT[64][72];   // [key][q-row]
    __shared__ float red[64][16];   // per-q-row cross-thread partials

    const int q0 = qt * 64;
    {
        const int row = t >> 2, d0 = (t & 3) * 8;
        const float* qp = q + ((size_t)b * Mn + q0 + row) * Cn + h * Dn + d0;
        float4 a0 = *(const float4*)qp, a1 = *(const float4*)(qp + 4);
        qT[d0 + 0][row] = a0.x; qT[d0 + 1][row] = a0.y; qT[d0 + 2][row] = a0.z; qT[d0 + 3][row] = a0.w;
        qT[d0 + 4][row] = a1.x; qT[d0 + 5][row] = a1.y; qT[d0 + 6][row] = a1.z; qT[d0 + 7][row] = a1.w;
    }

    const float scale = 0.17677669529663687f;  // 1/sqrt(32)
    float m_i[4], l_i[4], acc[4][2];
#pragma unroll
    for (int i = 0; i < 4; i++) { m_i[i] = -1e30f; l_i[i] = 0.f; acc[i][0] = 0.f; acc[i][1] = 0.f; }

    for (int kt = 0; kt < 2; kt++) {
        __syncthreads();  // qT visible (kt=0); psT/kT/vsm reads done (kt=1)
        {
            const int row = t >> 2, d0 = (t & 3) * 8;
            const int k0 = seg * 128 + kt * 64;
            const float* kp = kbuf + ((size_t)b * Mn + k0 + row) * Cn + h * Dn + d0;
            float4 a0 = *(const float4*)kp, a1 = *(const float4*)(kp + 4);
            kT[d0 + 0][row] = a0.x; kT[d0 + 1][row] = a0.y; kT[d0 + 2][row] = a0.z; kT[d0 + 3][row] = a0.w;
            kT[d0 + 4][row] = a1.x; kT[d0 + 5][row] = a1.y; kT[d0 + 6][row] = a1.z; kT[d0 + 7][row] = a1.w;
            const float* vp = vbuf + ((size_t)b * Mn + k0 + row) * Cn + h * Dn + d0;
            *(float4*)&vsm[row][d0] = *(const float4*)vp;
            *(float4*)&vsm[row][d0 + 4] = *(const float4*)(vp + 4);
        }
        __syncthreads();

        float s[4][4] = {};
#pragma unroll 8
        for (int d = 0; d < 32; d++) {
            float4 qv = *(const float4*)&qT[d][ty * 4];
            float4 kv = *(const float4*)&kT[d][tx * 4];
            float qa[4] = {qv.x, qv.y, qv.z, qv.w};
            float ka[4] = {kv.x, kv.y, kv.z, kv.w};
#pragma unroll
            for (int i = 0; i < 4; i++)
#pragma unroll
                for (int j = 0; j < 4; j++) s[i][j] += qa[i] * ka[j];
        }
        float tmax[4];
#pragma unroll
        for (int i = 0; i < 4; i++) {
            s[i][0] *= scale; s[i][1] *= scale; s[i][2] *= scale; s[i][3] *= scale;
            tmax[i] = fmaxf(fmaxf(s[i][0], s[i][1]), fmaxf(s[i][2], s[i][3]));
        }
#pragma unroll
        for (int i = 0; i < 4; i++) red[ty * 4 + i][tx] = tmax[i];
        __syncthreads();
        float nm[4];
#pragma unroll
        for (int i = 0; i < 4; i++) {
            const int row = ty * 4 + i;
            float mx = m_i[i];
#pragma unroll
            for (int xj = 0; xj < 16; xj++) mx = fmaxf(mx, red[row][xj]);
            nm[i] = mx;
        }
        __syncthreads();  // red reads done before sum-phase writes
        float tsum[4];
#pragma unroll
        for (int i = 0; i < 4; i++) {
            float p0 = __expf(s[i][0] - nm[i]);
            float p1 = __expf(s[i][1] - nm[i]);
            float p2 = __expf(s[i][2] - nm[i]);
            float p3 = __expf(s[i][3] - nm[i]);
            s[i][0] = p0; s[i][1] = p1; s[i][2] = p2; s[i][3] = p3;
            tsum[i] = p0 + p1 + p2 + p3;
        }
#pragma unroll
        for (int kk = 0; kk < 4; kk++)
            *(float4*)&psT[tx * 4 + kk][ty * 4] = make_float4(s[0][kk], s[1][kk], s[2][kk], s[3][kk]);
#pragma unroll
        for (int i = 0; i < 4; i++) red[ty * 4 + i][tx] = tsum[i];
        __syncthreads();
#pragma unroll
        for (int i = 0; i < 4; i++) {
            const int row = ty * 4 + i;
            float rs = 0.f;
#pragma unroll
            for (int xj = 0; xj < 16; xj++) rs += red[row][xj];
            const float r = __expf(m_i[i] - nm[i]);
            l_i[i] = l_i[i] * r + rs;
            m_i[i] = nm[i];
            acc[i][0] *= r; acc[i][1] *= r;
        }
#pragma unroll 8
        for (int k = 0; k < 64; k++) {
            float4 pv = *(const float4*)&psT[k][ty * 4];
            float2 vv = *(const float2*)&vsm[k][tx * 2];
            acc[0][0] += pv.x * vv.x; acc[0][1] += pv.x * vv.y;
            acc[1][0] += pv.y * vv.x; acc[1][1] += pv.y * vv.y;
            acc[2][0] += pv.z * vv.x; acc[2][1] += pv.z * vv.y;
            acc[3][0] += pv.w * vv.x; acc[3][1] += pv.w * vv.y;
        }
    }
#pragma unroll
    for (int i = 0; i < 4; i++) {
        const int m = q0 + ty * 4 + i;
        const size_t pr = (((size_t)seg * Bn + b) * Hn + h) * Mn + m;
        if (tx == 0) { pm[pr] = m_i[i]; pl[pr] = l_i[i]; }
        *(float2*)(pacc + pr * 32 + tx * 2) = make_float2(acc[i][0], acc[i][1]);
    }
}

__global__ __launch_bounds__(256) void k_comb(
    const float* __restrict__ pacc, const float* __restrict__ pm, const float* __restrict__ pl,
    float* __restrict__ att)
{
    const int t = threadIdx.x;
    const size_t row = (size_t)blockIdx.x * 8 + (t >> 5);  // (b*8+h)*1024 + m
    const int j = t & 31;
    float M = -1e30f;
#pragma unroll
    for (int s = 0; s < SEG; s++) M = fmaxf(M, pm[(size_t)s * 32768 + row]);
    float L = 0.f, a = 0.f;
#pragma unroll
    for (int s = 0; s < SEG; s++) {
        const float w = __expf(pm[(size_t)s * 32768 + row] - M);
        L += w * pl[(size_t)s * 32768 + row];
        a += w * pacc[((size_t)s * 32768 + row) * 32 + j];
    }
    const int bh = (int)(row >> 10);
    const int mrow = (int)(row & 1023);
    const int b = bh >> 3, h = bh & 7;
    att[((size_t)b * Mn + mrow) * Cn + h * 32 + j] = a / L;
}

// ---------------------------------------------------------------------------
// to_basis #2 over far rows only
// ---------------------------------------------------------------------------
__global__ __launch_bounds__(256) void k_tobasis2(
    const float* __restrict__ evf, const float* __restrict__ xo, float* __restrict__ part)
{
    const int mch = blockIdx.x, ct = blockIdx.y, b = blockIdx.z;
    const int m0 = mch * (Mn / MCH);
    const int c0 = ct * 128;
    __shared__ float ev[32][128];
    __shared__ float xm[32][128];
    const int t = threadIdx.x, tx = t & 15, ty = t >> 4;
    float acc[8][8];
#pragma unroll
    for (int i = 0; i < 8; i++)
#pragma unroll
        for (int j = 0; j < 8; j++) acc[i][j] = 0.f;
    const int lr = t >> 3, lc = (t & 7) * 16;
    for (int s = 0; s < Mn / MCH; s += 32) {
        const size_t mrow = (size_t)b * Mn + m0 + s + lr;
        {
            const float* es = evf + mrow * Kn + lc;
            *(float4*)&ev[lr][lc]      = *(const float4*)es;
            *(float4*)&ev[lr][lc + 4]  = *(const float4*)(es + 4);
            *(float4*)&ev[lr][lc + 8]  = *(const float4*)(es + 8);
            *(float4*)&ev[lr][lc + 12] = *(const float4*)(es + 12);
            const float* xs = xo + mrow * Cn + c0 + lc;
            *(float4*)&xm[lr][lc]      = *(const float4*)xs;
            *(float4*)&xm[lr][lc + 4]  = *(const float4*)(xs + 4);
            *(float4*)&xm[lr][lc + 8]  = *(const float4*)(xs + 8);
            *(float4*)&xm[lr][lc + 12] = *(const float4*)(xs + 12);
        }
        __syncthreads();
#pragma unroll 4
        for (int nn = 0; nn < 32; nn++) {
            float4 e0 = *(const float4*)&ev[nn][ty * 4];
            float4 e1 = *(const float4*)&ev[nn][64 + ty * 4];
            float4 x0 = *(const float4*)&xm[nn][tx * 4];
            float4 x1 = *(const float4*)&xm[nn][64 + tx * 4];
            float ee[8] = {e0.x, e0.y, e0.z, e0.w, e1.x, e1.y, e1.z, e1.w};
            float xx[8] = {x0.x, x0.y, x0.z, x0.w, x1.x, x1.y, x1.z, x1.w};
#pragma unroll
            for (int i = 0; i < 8; i++)
#pragma unroll
                for (int j = 0; j < 8; j++) acc[i][j] += ee[i] * xx[j];
        }
        __syncthreads();
    }
    float* dst = part + ((size_t)b * MCH + mch) * (Kn * Cn);
#pragma unroll
    for (int i = 0; i < 8; i++) {
        const int k = (i < 4) ? (ty * 4 + i) : (64 + ty * 4 + i - 4);
        *(float4*)(dst + (size_t)k * Cn + c0 + tx * 4) =
            make_float4(acc[i][0], acc[i][1], acc[i][2], acc[i][3]);
        *(float4*)(dst + (size_t)k * Cn + c0 + 64 + tx * 4) =
            make_float4(acc[i][4], acc[i][5], acc[i][6], acc[i][7]);
    }
}

// ---------------------------------------------------------------------------
// from_basis #2: out[b,n,c] = out_w[c] * sum_k evecs[b,n,k]*spec2'[b,k,c]
// ---------------------------------------------------------------------------
__global__ __launch_bounds__(256) void k_frombasis2(
    const float* __restrict__ evecs, const float* __restrict__ spec,
    const float* __restrict__ outw, float* __restrict__ out)
{
    const int nt = blockIdx.x, ct = blockIdx.y, b = blockIdx.z;
    const int n0 = nt * 128, c0 = ct * 128;
    __shared__ float evT[32][132];
    __shared__ float sp[32][128];
    const int t = threadIdx.x, tx = t & 15, ty = t >> 4;
    float acc[8][8];
#pragma unroll
    for (int i = 0; i < 8; i++)
#pragma unroll
        for (int j = 0; j < 8; j++) acc[i][j] = 0.f;
    const int en = t >> 1, ek0 = (t & 1) * 16;
    const int sr = t >> 3, sc = (t & 7) * 16;
    for (int k0 = 0; k0 < Kn; k0 += 32) {
        {
            const float* es = evecs + ((size_t)b * Nn + n0 + en) * Kn + k0 + ek0;
            float4 a0 = *(const float4*)es, a1 = *(const float4*)(es + 4);
            float4 a2 = *(const float4*)(es + 8), a3 = *(const float4*)(es + 12);
            evT[ek0 + 0][en] = a0.x; evT[ek0 + 1][en] = a0.y; evT[ek0 + 2][en] = a0.z; evT[ek0 + 3][en] = a0.w;
            evT[ek0 + 4][en] = a1.x; evT[ek0 + 5][en] = a1.y; evT[ek0 + 6][en] = a1.z; evT[ek0 + 7][en] = a1.w;
            evT[ek0 + 8][en] = a2.x; evT[ek0 + 9][en] = a2.y; evT[ek0 + 10][en] = a2.z; evT[ek0 + 11][en] = a2.w;
            evT[ek0 + 12][en] = a3.x; evT[ek0 + 13][en] = a3.y; evT[ek0 + 14][en] = a3.z; evT[ek0 + 15][en] = a3.w;
            const float* ss = spec + ((size_t)b * Kn + k0 + sr) * Cn + c0 + sc;
            *(float4*)&sp[sr][sc]      = *(const float4*)ss;
            *(float4*)&sp[sr][sc + 4]  = *(const float4*)(ss + 4);
            *(float4*)&sp[sr][sc + 8]  = *(const float4*)(ss + 8);
            *(float4*)&sp[sr][sc + 12] = *(const float4*)(ss + 12);
        }
        __syncthreads();
#pragma unroll 4
        for (int kk2 = 0; kk2 < 32; kk2++) {
            float4 e0 = *(const float4*)&evT[kk2][ty * 4];
            float4 e1 = *(const float4*)&evT[kk2][64 + ty * 4];
            float4 s0 = *(const float4*)&sp[kk2][tx * 4];
            float4 s1 = *(const float4*)&sp[kk2][64 + tx * 4];
            float ee[8] = {e0.x, e0.y, e0.z, e0.w, e1.x, e1.y, e1.z, e1.w};
            float sv[8] = {s0.x, s0.y, s0.z, s0.w, s1.x, s1.y, s1.z, s1.w};
#pragma unroll
            for (int i = 0; i < 8; i++)
#pragma unroll
                for (int j = 0; j < 8; j++) acc[i][j] += ee[i] * sv[j];
        }
        __syncthreads();
    }
    float ow[8];
#pragma unroll
    for (int j = 0; j < 8; j++) {
        const int c = c0 + ((j < 4) ? (tx * 4 + j) : (64 + tx * 4 + j - 4));
        ow[j] = fmaxf(outw[c], 1e-8f);
    }
#pragma unroll
    for (int i = 0; i < 8; i++) {
        const int n = n0 + ((i < 4) ? (ty * 4 + i) : (64 + ty * 4 + i - 4));
        float* od = out + ((size_t)b * Nn + n) * Cn + c0;
        *(float4*)(od + tx * 4) =
            make_float4(acc[i][0] * ow[0], acc[i][1] * ow[1], acc[i][2] * ow[2], acc[i][3] * ow[3]);
        *(float4*)(od + 64 + tx * 4) =
            make_float4(acc[i][4] * ow[4], acc[i][5] * ow[5], acc[i][6] * ow[6], acc[i][7] * ow[7]);
    }
}

// ---------------------------------------------------------------------------
extern "C" void kernel_launch(void* const* d_in, const int* in_sizes, int n_in,
                              void* d_out, int out_size, void* d_ws, size_t ws_size,
                              hipStream_t stream)
{
    const float* x     = (const float*)d_in[0];
    const float* mass  = (const float*)d_in[1];
    const float* evals = (const float*)d_in[2];
    const float* evecs = (const float*)d_in[3];
    const int*   far   = (const int*)d_in[4];
    const float* t_in  = (const float*)d_in[5];
    const float* t_out = (const float*)d_in[6];
    const float* gn_w  = (const float*)d_in[7];
    const float* gn_b  = (const float*)d_in[8];
    const float* Wq    = (const float*)d_in[9];
    const float* bq    = (const float*)d_in[10];
    const float* Wk    = (const float*)d_in[11];
    const float* bk    = (const float*)d_in[12];
    const float* Wv    = (const float*)d_in[13];
    const float* bv    = (const float*)d_in[14];
    const float* Wo    = (const float*)d_in[15];
    const float* bo    = (const float*)d_in[16];
    const float* outw  = (const float*)d_in[17];
    float* out = (float*)d_out;
    float* ws = (float*)d_ws;

    // --- Tight lifetime-aliased workspace layout (high-water 14,815,488 floats
    // = 56.5 MiB; round-4's 68.2 MB overflowed the workspace). Lifetimes:
    //   A: part1(k1-2) -> pacc(k8-9) -> part2(k11-12)
    //   spec1(k2-4) / spec2(k11-12) share; xfar(k4-5) / xo(k9-10) share;
    //   xn(k5-6) / att(k8-9) share; q,kk,v(k6-7) exclusive.
    float* A     = ws;                      // 8,388,608
    float* evf   = ws    + 8388608;         //   524,288 (k3..k10)
    float* massf = evf   + 524288;          //     4,096 (k3..k9)
    float* gst   = massf + 4096;            //       256
    float* pm    = gst   + 256;             //   262,144 (k7..k8)
    float* pl    = pm    + 262144;          //   262,144
    float* spec1 = pl    + 262144;          //   131,072
    float* xfar  = spec1 + 131072;          // 1,048,576
    float* xn    = xfar  + 1048576;         // 1,048,576
    float* q     = xn    + 1048576;         // 1,048,576
    float* kk    = q     + 1048576;         // 1,048,576
    float* v     = kk    + 1048576;         // 1,048,576  (ends at 14,815,488)
    float* pacc  = A;
    float* part2 = A;
    float* spec2 = spec1;   // spec1 dead after from_basis1
    float* xo    = xfar;    // xfar dead after gnapply
    float* att   = xn;      // xn dead after QKV gemm

    k_tobasis1<<<dim3(NCH, 2, Bn), 256, 0, stream>>>(x, mass, evecs, A);
    k_reduce<<<Bn * Kn, Cn, 0, stream>>>(A, NCH, evals, t_in, spec1);
    k_gather<<<Bn * Mn, Kn, 0, stream>>>(evecs, mass, far, evf, massf);
    {
        G3 g{};
        g.W[0] = spec1; g.bias[0] = nullptr; g.out[0] = xfar;
        k_gemm64<128, true, false><<<dim3(64, 4, 1), 256, 0, stream>>>(evf, g, nullptr);
    }
    k_gnstats<<<Bn * 32, 256, 0, stream>>>(xfar, gst);
    k_gnapply<<<1024, 256, 0, stream>>>(xfar, gst, gn_w, gn_b, xn);
    {
        G3 g{};
        g.W[0] = Wq; g.W[1] = Wk; g.W[2] = Wv;
        g.bias[0] = bq; g.bias[1] = bk; g.bias[2] = bv;
        g.out[0] = q; g.out[1] = kk; g.out[2] = v;
        k_gemm64<256, false, false><<<dim3(64, 4, 3), 256, 0, stream>>>(xn, g, nullptr);
    }
    k_attn<<<dim3(16, SEG, 32), 256, 0, stream>>>(q, kk, v, pacc, pm, pl);
    k_comb<<<4096, 256, 0, stream>>>(pacc, pm, pl, att);
    {
        G3 g{};
        g.W[0] = Wo; g.bias[0] = bo; g.out[0] = xo;
        k_gemm64<256, false, true><<<dim3(64, 4, 1), 256, 0, stream>>>(att, g, massf);
    }
    k_tobasis2<<<dim3(MCH, 2, Bn), 256, 0, stream>>>(evf, xo, part2);
    k_reduce<<<Bn * Kn, Cn, 0, stream>>>(part2, MCH, evals, t_out, spec2);
    k_frombasis2<<<dim3(256, 2, Bn), 256, 0, stream>>>(evecs, spec2, outw, out);
}